// Round 1
// baseline (833.997 us; speedup 1.0000x reference)
//
#include <hip/hip_runtime.h>

// ResGCNBlock: out = LN(relu(scatter_add(norm * (xW^T+b)[row] -> col))) + x
// N=50000, D=128, E=800000, fp32. Baseline correctness-first implementation.

#define D 128

// ---------- WT[k][j] = W[j][k] ----------
__global__ void k_transpose_w(const float* __restrict__ W, float* __restrict__ WT) {
    int idx = blockIdx.x * 256 + threadIdx.x;   // 16384 elements total
    int k = idx >> 7, j = idx & 127;
    WT[k * D + j] = W[j * D + k];
}

// ---------- deg histogram over edge sources ----------
__global__ void k_deg(const int* __restrict__ row, int E, unsigned* __restrict__ deg) {
    int e = blockIdx.x * 256 + threadIdx.x;
    if (e < E) atomicAdd(&deg[row[e]], 1u);
}

// ---------- dis = (deg+1)^-0.5  (+1 = self loop) ----------
__global__ void k_dis(const unsigned* __restrict__ deg, float* __restrict__ dis, int n) {
    int i = blockIdx.x * 256 + threadIdx.x;
    if (i < n) dis[i] = rsqrtf((float)deg[i] + 1.0f);
}

// ---------- h = x @ W^T + b ; 8 rows per block, 256 threads ----------
__global__ void k_gemm(const float* __restrict__ x, const float* __restrict__ WT,
                       const float* __restrict__ bias, float* __restrict__ h, int nrows) {
    __shared__ float xs[8][D];
    int t = threadIdx.x;
    int n0 = blockIdx.x * 8;
    #pragma unroll
    for (int i = 0; i < 4; i++) {
        int idx = i * 256 + t;
        int r = idx >> 7, c = idx & 127;
        int gr = n0 + r;
        xs[r][c] = (gr < nrows) ? x[(size_t)gr * D + c] : 0.0f;
    }
    __syncthreads();
    int j = t & 127, half = t >> 7;           // half-block: 4 rows each
    float acc[4];
    float bj = bias[j];
    #pragma unroll
    for (int i = 0; i < 4; i++) acc[i] = bj;
    const float* xr = &xs[half * 4][0];
    #pragma unroll 4
    for (int k = 0; k < D; k++) {
        float w = WT[k * D + j];              // coalesced across j, L1/L2-hot
        acc[0] += xr[0 * D + k] * w;          // LDS broadcast reads
        acc[1] += xr[1 * D + k] * w;
        acc[2] += xr[2 * D + k] * w;
        acc[3] += xr[3 * D + k] * w;
    }
    #pragma unroll
    for (int i = 0; i < 4; i++) {
        int gr = n0 + half * 4 + i;
        if (gr < nrows) h[(size_t)gr * D + j] = acc[i];
    }
}

// ---------- scatter: agg[col] += dis[row]*dis[col] * h[row] ----------
// one wave per edge; lane l handles float2 at cols (2l, 2l+1)
__global__ void k_scatter(const int* __restrict__ ei, int E,
                          const float* __restrict__ dis,
                          const float* __restrict__ h,
                          float* __restrict__ agg) {
    int w = threadIdx.x >> 6, l = threadIdx.x & 63;
    int e = blockIdx.x * 4 + w;
    if (e >= E) return;
    int r = ei[e];
    int c = ei[E + e];
    float norm = dis[r] * dis[c];
    float2 hv = ((const float2*)h)[(size_t)r * 64 + l];
    float* ap = &agg[(size_t)c * D + 2 * l];
    unsafeAtomicAdd(ap,     norm * hv.x);   // global_atomic_add_f32
    unsafeAtomicAdd(ap + 1, norm * hv.y);
}

// ---------- epilogue: +self-loop, relu, LN, gamma/beta, +x ----------
// one wave per row; agg lives in `out` and is overwritten in place
__global__ void k_final(const float* __restrict__ x, const float* __restrict__ h,
                        const float* __restrict__ dis,
                        const float* __restrict__ gamma, const float* __restrict__ beta,
                        float* __restrict__ out, int n) {
    int w = threadIdx.x >> 6, l = threadIdx.x & 63;
    int row = blockIdx.x * 4 + w;
    if (row >= n) return;
    float dn = dis[row];
    float sn = dn * dn;                        // self-loop norm
    float2 a  = ((const float2*)out)[(size_t)row * 64 + l];
    float2 hh = ((const float2*)h)[(size_t)row * 64 + l];
    float v0 = a.x + sn * hh.x;  v0 = v0 > 0.0f ? v0 : 0.0f;
    float v1 = a.y + sn * hh.y;  v1 = v1 > 0.0f ? v1 : 0.0f;
    float s1 = v0 + v1;
    float s2 = v0 * v0 + v1 * v1;
    #pragma unroll
    for (int m = 32; m >= 1; m >>= 1) {
        s1 += __shfl_xor(s1, m, 64);
        s2 += __shfl_xor(s2, m, 64);
    }
    float mean = s1 * (1.0f / 128.0f);
    float var  = s2 * (1.0f / 128.0f) - mean * mean;   // population var (jnp.var)
    float rstd = rsqrtf(var + 1e-5f);
    float2 g  = ((const float2*)gamma)[l];
    float2 bb = ((const float2*)beta)[l];
    float2 xx = ((const float2*)x)[(size_t)row * 64 + l];
    float2 o;
    o.x = (v0 - mean) * rstd * g.x + bb.x + xx.x;
    o.y = (v1 - mean) * rstd * g.y + bb.y + xx.y;
    ((float2*)out)[(size_t)row * 64 + l] = o;
}

extern "C" void kernel_launch(void* const* d_in, const int* in_sizes, int n_in,
                              void* d_out, int out_size, void* d_ws, size_t ws_size,
                              hipStream_t stream) {
    const float* x     = (const float*)d_in[0];
    const int*   ei    = (const int*)d_in[1];   // [2, E] int
    const float* W     = (const float*)d_in[2];
    const float* bias  = (const float*)d_in[3];
    const float* gamma = (const float*)d_in[4];
    const float* beta  = (const float*)d_in[5];
    int N = in_sizes[0] / D;
    int E = in_sizes[1] / 2;

    char* ws = (char*)d_ws;
    size_t off = 0;
    float* h = (float*)(ws + off);      off += (size_t)N * D * sizeof(float);   // 25.6 MB
    float* WT = (float*)(ws + off);     off += (size_t)D * D * sizeof(float);   // 64 KB
    unsigned* deg = (unsigned*)(ws + off); off += (size_t)N * sizeof(unsigned); // 200 KB
    float* dis = (float*)(ws + off);    off += (size_t)N * sizeof(float);       // 200 KB
    float* out = (float*)d_out;         // doubles as agg accumulator

    hipMemsetAsync(out, 0, (size_t)N * D * sizeof(float), stream);
    hipMemsetAsync(deg, 0, (size_t)N * sizeof(unsigned), stream);

    k_transpose_w<<<64, 256, 0, stream>>>(W, WT);
    k_deg<<<(E + 255) / 256, 256, 0, stream>>>(ei, E, deg);
    k_dis<<<(N + 255) / 256, 256, 0, stream>>>(deg, dis, N);
    k_gemm<<<(N + 7) / 8, 256, 0, stream>>>(x, WT, bias, h, N);
    k_scatter<<<(E + 3) / 4, 256, 0, stream>>>(ei, E, dis, h, out);
    k_final<<<(N + 3) / 4, 256, 0, stream>>>(x, h, dis, gamma, beta, out, N);
}

// Round 2
// 330.420 us; speedup vs baseline: 2.5241x; 2.5241x over previous
//
#include <hip/hip_runtime.h>

// ResGCNBlock: out = LN(relu(scatter_add(norm * (xW^T+b)[row] -> col))) + x
// N=50000, D=128, E=800000, fp32.
// Round 2: CSR two-phase aggregation (no fp atomics) + fused epilogue.

#define D 128

// ---------- WT[k][j] = W[j][k] ----------
__global__ void k_transpose_w(const float* __restrict__ W, float* __restrict__ WT) {
    int idx = blockIdx.x * 256 + threadIdx.x;   // 16384 elements total
    int k = idx >> 7, j = idx & 127;
    WT[k * D + j] = W[j * D + k];
}

// ---------- histograms: deg by source (for dis), cnt by dest (for CSR) ----------
__global__ void k_hist(const int* __restrict__ ei, int E,
                       unsigned* __restrict__ deg, unsigned* __restrict__ cnt) {
    int e = blockIdx.x * 256 + threadIdx.x;
    if (e < E) {
        atomicAdd(&deg[ei[e]], 1u);        // source
        atomicAdd(&cnt[ei[E + e]], 1u);    // dest
    }
}

// ---------- dis = (deg+1)^-0.5  (+1 = self loop) ----------
__global__ void k_dis(const unsigned* __restrict__ deg, float* __restrict__ dis, int n) {
    int i = blockIdx.x * 256 + threadIdx.x;
    if (i < n) dis[i] = rsqrtf((float)deg[i] + 1.0f);
}

// ---------- scan pass 1: per-block partial sums of cnt ----------
__global__ void k_partial(const unsigned* __restrict__ cnt, int n,
                          unsigned* __restrict__ partial) {
    __shared__ unsigned s[256];
    int t = threadIdx.x;
    int i = blockIdx.x * 256 + t;
    s[t] = (i < n) ? cnt[i] : 0u;
    __syncthreads();
    #pragma unroll
    for (int d = 128; d > 0; d >>= 1) {
        if (t < d) s[t] += s[t + d];
        __syncthreads();
    }
    if (t == 0) partial[blockIdx.x] = s[0];
}

// ---------- scan pass 2: exclusive scan of partials (nb <= 256) ----------
__global__ void k_scanp(unsigned* __restrict__ partial, int nb) {
    __shared__ unsigned s[256];
    int t = threadIdx.x;
    unsigned v = (t < nb) ? partial[t] : 0u;
    s[t] = v;
    __syncthreads();
    #pragma unroll
    for (int d = 1; d < 256; d <<= 1) {
        unsigned u = (t >= d) ? s[t - d] : 0u;
        __syncthreads();
        s[t] += u;
        __syncthreads();
    }
    if (t < nb) partial[t] = s[t] - v;      // exclusive
}

// ---------- scan pass 3: block-local exclusive scan + offset -> rowptr ----------
__global__ void k_rowptr(const unsigned* __restrict__ cnt,
                         const unsigned* __restrict__ partial,
                         int n, int E, int* __restrict__ rowptr) {
    __shared__ unsigned s[256];
    int t = threadIdx.x;
    int i = blockIdx.x * 256 + t;
    unsigned v = (i < n) ? cnt[i] : 0u;
    s[t] = v;
    __syncthreads();
    #pragma unroll
    for (int d = 1; d < 256; d <<= 1) {
        unsigned u = (t >= d) ? s[t - d] : 0u;
        __syncthreads();
        s[t] += u;
        __syncthreads();
    }
    if (i < n) rowptr[i] = (int)(partial[blockIdx.x] + s[t] - v);
    if (blockIdx.x == 0 && t == 0) rowptr[n] = E;
}

// ---------- bucket fill: srcs grouped by dest; cnt consumed as cursor ----------
__global__ void k_fill(const int* __restrict__ ei, int E,
                       const int* __restrict__ rowptr, unsigned* __restrict__ cnt,
                       int* __restrict__ srcs) {
    int e = blockIdx.x * 256 + threadIdx.x;
    if (e < E) {
        int r = ei[e];
        int c = ei[E + e];
        unsigned slot = atomicSub(&cnt[c], 1u) - 1u;   // unique in [0, count)
        srcs[rowptr[c] + (int)slot] = r;
    }
}

// ---------- h = x @ W^T + b ; 8 rows per block, 256 threads ----------
__global__ void k_gemm(const float* __restrict__ x, const float* __restrict__ WT,
                       const float* __restrict__ bias, float* __restrict__ h, int nrows) {
    __shared__ float xs[8][D];
    int t = threadIdx.x;
    int n0 = blockIdx.x * 8;
    #pragma unroll
    for (int i = 0; i < 4; i++) {
        int idx = i * 256 + t;
        int r = idx >> 7, c = idx & 127;
        int gr = n0 + r;
        xs[r][c] = (gr < nrows) ? x[(size_t)gr * D + c] : 0.0f;
    }
    __syncthreads();
    int j = t & 127, half = t >> 7;
    float acc[4];
    float bj = bias[j];
    #pragma unroll
    for (int i = 0; i < 4; i++) acc[i] = bj;
    const float* xr = &xs[half * 4][0];
    #pragma unroll 4
    for (int k = 0; k < D; k++) {
        float w = WT[k * D + j];
        acc[0] += xr[0 * D + k] * w;
        acc[1] += xr[1 * D + k] * w;
        acc[2] += xr[2 * D + k] * w;
        acc[3] += xr[3 * D + k] * w;
    }
    #pragma unroll
    for (int i = 0; i < 4; i++) {
        int gr = n0 + half * 4 + i;
        if (gr < nrows) h[(size_t)gr * D + j] = acc[i];
    }
}

// ---------- fused gather-aggregate + self-loop + relu + LN + residual ----------
// one wave per dest row; lane l owns cols (2l, 2l+1)
__global__ void k_agg(const float* __restrict__ x, const float* __restrict__ h,
                      const float* __restrict__ dis,
                      const int* __restrict__ rowptr, const int* __restrict__ srcs,
                      const float* __restrict__ gamma, const float* __restrict__ beta,
                      float* __restrict__ out, int n) {
    int w = threadIdx.x >> 6, l = threadIdx.x & 63;
    int row = blockIdx.x * 4 + w;
    if (row >= n) return;
    const float2* h2 = (const float2*)h;
    float dc = dis[row];
    // self-loop message: dis[row]^2 * h[row]
    float2 hs = h2[(size_t)row * 64 + l];
    float accx = dc * dc * hs.x;
    float accy = dc * dc * hs.y;
    int s0 = rowptr[row], s1 = rowptr[row + 1];
    for (int k = s0; k < s1; k++) {
        int r = srcs[k];                   // wave-uniform address -> broadcast
        float norm = dc * dis[r];
        float2 hv = h2[(size_t)r * 64 + l];
        accx += norm * hv.x;
        accy += norm * hv.y;
    }
    // relu
    float v0 = accx > 0.0f ? accx : 0.0f;
    float v1 = accy > 0.0f ? accy : 0.0f;
    // layernorm over 128 cols via wave shuffle reduce
    float s1r = v0 + v1;
    float s2r = v0 * v0 + v1 * v1;
    #pragma unroll
    for (int m = 32; m >= 1; m >>= 1) {
        s1r += __shfl_xor(s1r, m, 64);
        s2r += __shfl_xor(s2r, m, 64);
    }
    float mean = s1r * (1.0f / 128.0f);
    float var  = s2r * (1.0f / 128.0f) - mean * mean;
    float rstd = rsqrtf(var + 1e-5f);
    float2 g  = ((const float2*)gamma)[l];
    float2 bb = ((const float2*)beta)[l];
    float2 xx = ((const float2*)x)[(size_t)row * 64 + l];
    float2 o;
    o.x = (v0 - mean) * rstd * g.x + bb.x + xx.x;
    o.y = (v1 - mean) * rstd * g.y + bb.y + xx.y;
    ((float2*)out)[(size_t)row * 64 + l] = o;
}

extern "C" void kernel_launch(void* const* d_in, const int* in_sizes, int n_in,
                              void* d_out, int out_size, void* d_ws, size_t ws_size,
                              hipStream_t stream) {
    const float* x     = (const float*)d_in[0];
    const int*   ei    = (const int*)d_in[1];   // [2, E]
    const float* W     = (const float*)d_in[2];
    const float* bias  = (const float*)d_in[3];
    const float* gamma = (const float*)d_in[4];
    const float* beta  = (const float*)d_in[5];
    int N = in_sizes[0] / D;
    int E = in_sizes[1] / 2;
    int nb = (N + 255) / 256;                    // scan blocks (<=256 for N<=65536)

    char* ws = (char*)d_ws;
    size_t off = 0;
    float*    h       = (float*)(ws + off);    off += (size_t)N * D * sizeof(float);
    float*    WT      = (float*)(ws + off);    off += (size_t)D * D * sizeof(float);
    unsigned* deg     = (unsigned*)(ws + off); off += (size_t)N * sizeof(unsigned);
    unsigned* cnt     = (unsigned*)(ws + off); off += (size_t)N * sizeof(unsigned);
    float*    dis     = (float*)(ws + off);    off += (size_t)N * sizeof(float);
    int*      rowptr  = (int*)(ws + off);      off += (size_t)(N + 1) * sizeof(int);
    unsigned* partial = (unsigned*)(ws + off); off += 256 * sizeof(unsigned);
    int*      srcs    = (int*)(ws + off);      off += (size_t)E * sizeof(int);
    float*    out     = (float*)d_out;

    hipMemsetAsync(deg, 0, (size_t)N * sizeof(unsigned), stream);
    hipMemsetAsync(cnt, 0, (size_t)N * sizeof(unsigned), stream);

    k_transpose_w<<<64, 256, 0, stream>>>(W, WT);
    k_hist<<<(E + 255) / 256, 256, 0, stream>>>(ei, E, deg, cnt);
    k_dis<<<(N + 255) / 256, 256, 0, stream>>>(deg, dis, N);
    k_partial<<<nb, 256, 0, stream>>>(cnt, N, partial);
    k_scanp<<<1, 256, 0, stream>>>(partial, nb);
    k_rowptr<<<nb, 256, 0, stream>>>(cnt, partial, N, E, rowptr);
    k_fill<<<(E + 255) / 256, 256, 0, stream>>>(ei, E, rowptr, cnt, srcs);
    k_gemm<<<(N + 7) / 8, 256, 0, stream>>>(x, WT, bias, h, N);
    k_agg<<<(N + 3) / 4, 256, 0, stream>>>(x, h, dis, rowptr, srcs, gamma, beta, out, N);
}

// Round 3
// 289.843 us; speedup vs baseline: 2.8774x; 1.1400x over previous
//
#include <hip/hip_runtime.h>

// ResGCNBlock: out = LN(relu(scatter_add(norm * (xW^T+b)[row] -> col))) + x
// N=50000, D=128, E=800000, fp32.
// Round 3: bf16 h (halves gather traffic) + MFMA GEMM + shuffle-broadcast agg.

#define D 128

typedef short bf16x8 __attribute__((ext_vector_type(8)));
typedef float f32x4 __attribute__((ext_vector_type(4)));

__device__ __forceinline__ unsigned short f2bf(float f) {
    unsigned u = __float_as_uint(f);
    return (unsigned short)((u + 0x7fffu + ((u >> 16) & 1u)) >> 16);
}
__device__ __forceinline__ float bf2f_lo(unsigned v) {  // low 16 bits -> float
    return __uint_as_float(v << 16);
}
__device__ __forceinline__ float bf2f_hi(unsigned v) {  // high 16 bits -> float
    return __uint_as_float(v & 0xffff0000u);
}

// ---------- fp32 -> bf16 cast, 4 elements/thread ----------
__global__ void k_cast4(const float4* __restrict__ src, ushort4* __restrict__ dst, int n4) {
    int i = blockIdx.x * 256 + threadIdx.x;
    if (i < n4) {
        float4 v = src[i];
        ushort4 o;
        o.x = f2bf(v.x); o.y = f2bf(v.y); o.z = f2bf(v.z); o.w = f2bf(v.w);
        dst[i] = o;
    }
}

// ---------- histograms: deg by source (for dis), cnt by dest (for CSR) ----------
__global__ void k_hist(const int* __restrict__ ei, int E,
                       unsigned* __restrict__ deg, unsigned* __restrict__ cnt) {
    int e = blockIdx.x * 256 + threadIdx.x;
    if (e < E) {
        atomicAdd(&deg[ei[e]], 1u);        // source
        atomicAdd(&cnt[ei[E + e]], 1u);    // dest
    }
}

// ---------- dis = (deg+1)^-0.5  (+1 = self loop) ----------
__global__ void k_dis(const unsigned* __restrict__ deg, float* __restrict__ dis, int n) {
    int i = blockIdx.x * 256 + threadIdx.x;
    if (i < n) dis[i] = rsqrtf((float)deg[i] + 1.0f);
}

// ---------- scan pass 1: per-block partial sums of cnt ----------
__global__ void k_partial(const unsigned* __restrict__ cnt, int n,
                          unsigned* __restrict__ partial) {
    __shared__ unsigned s[256];
    int t = threadIdx.x;
    int i = blockIdx.x * 256 + t;
    s[t] = (i < n) ? cnt[i] : 0u;
    __syncthreads();
    #pragma unroll
    for (int d = 128; d > 0; d >>= 1) {
        if (t < d) s[t] += s[t + d];
        __syncthreads();
    }
    if (t == 0) partial[blockIdx.x] = s[0];
}

// ---------- scan pass 2: exclusive scan of partials (nb <= 256) ----------
__global__ void k_scanp(unsigned* __restrict__ partial, int nb) {
    __shared__ unsigned s[256];
    int t = threadIdx.x;
    unsigned v = (t < nb) ? partial[t] : 0u;
    s[t] = v;
    __syncthreads();
    #pragma unroll
    for (int d = 1; d < 256; d <<= 1) {
        unsigned u = (t >= d) ? s[t - d] : 0u;
        __syncthreads();
        s[t] += u;
        __syncthreads();
    }
    if (t < nb) partial[t] = s[t] - v;      // exclusive
}

// ---------- scan pass 3: block-local exclusive scan + offset -> rowptr ----------
__global__ void k_rowptr(const unsigned* __restrict__ cnt,
                         const unsigned* __restrict__ partial,
                         int n, int E, int* __restrict__ rowptr) {
    __shared__ unsigned s[256];
    int t = threadIdx.x;
    int i = blockIdx.x * 256 + t;
    unsigned v = (i < n) ? cnt[i] : 0u;
    s[t] = v;
    __syncthreads();
    #pragma unroll
    for (int d = 1; d < 256; d <<= 1) {
        unsigned u = (t >= d) ? s[t - d] : 0u;
        __syncthreads();
        s[t] += u;
        __syncthreads();
    }
    if (i < n) rowptr[i] = (int)(partial[blockIdx.x] + s[t] - v);
    if (blockIdx.x == 0 && t == 0) rowptr[n] = E;
}

// ---------- bucket fill: srcs grouped by dest; cnt consumed as cursor ----------
__global__ void k_fill(const int* __restrict__ ei, int E,
                       const int* __restrict__ rowptr, unsigned* __restrict__ cnt,
                       int* __restrict__ srcs) {
    int e = blockIdx.x * 256 + threadIdx.x;
    if (e < E) {
        int r = ei[e];
        int c = ei[E + e];
        unsigned slot = atomicSub(&cnt[c], 1u) - 1u;   // unique in [0, count)
        srcs[rowptr[c] + (int)slot] = r;
    }
}

// ---------- h = x @ W^T + b via MFMA, output bf16 ----------
// 4 waves/block, each wave computes a 16x128 slab of h. Fragments straight
// from global: A = x_bf rows (contiguous k), B = W_bf rows (W[n][k], contiguous k).
__global__ void k_gemm_mfma(const unsigned short* __restrict__ xb,
                            const unsigned short* __restrict__ wb,
                            const float* __restrict__ bias,
                            unsigned short* __restrict__ hb, int nrows) {
    int wid = threadIdx.x >> 6, lane = threadIdx.x & 63;
    int m0 = (blockIdx.x * 4 + wid) * 16;
    if (m0 >= nrows) return;
    int lo16 = lane & 15, quad = lane >> 4;
    const unsigned short* arow = xb + (size_t)(m0 + lo16) * D + quad * 8;
    bf16x8 a[4];
    #pragma unroll
    for (int kt = 0; kt < 4; kt++)
        a[kt] = *(const bf16x8*)(arow + kt * 32);      // A[m=lo16][k=kt*32+quad*8 ..+7]
    #pragma unroll
    for (int nt = 0; nt < 8; nt++) {
        int n0 = nt * 16;
        const unsigned short* brow = wb + (size_t)(n0 + lo16) * D + quad * 8;
        float bj = bias[n0 + lo16];                    // C col = lane&15
        f32x4 acc = {bj, bj, bj, bj};
        #pragma unroll
        for (int kt = 0; kt < 4; kt++) {
            bf16x8 b = *(const bf16x8*)(brow + kt * 32);
            acc = __builtin_amdgcn_mfma_f32_16x16x32_bf16(a[kt], b, acc, 0, 0, 0);
        }
        #pragma unroll
        for (int r = 0; r < 4; r++) {                  // C row = quad*4 + r
            int gr = m0 + quad * 4 + r;
            hb[(size_t)gr * D + n0 + lo16] = f2bf(acc[r]);
        }
    }
}

// ---------- fused gather-aggregate + self-loop + relu + LN + residual ----------
// one wave per dest row; lane l owns cols (2l, 2l+1); h is bf16 (4 B/lane/edge).
// srcs + dis[src] loaded 64-wide cooperatively, broadcast via shuffle.
__global__ void k_agg(const float* __restrict__ x, const unsigned short* __restrict__ hb,
                      const float* __restrict__ dis,
                      const int* __restrict__ rowptr, const int* __restrict__ srcs,
                      const float* __restrict__ gamma, const float* __restrict__ beta,
                      float* __restrict__ out, int n) {
    int w = threadIdx.x >> 6, l = threadIdx.x & 63;
    int row = blockIdx.x * 4 + w;
    if (row >= n) return;
    const unsigned* h2 = (const unsigned*)hb;          // 2 bf16 cols per load
    float dc = dis[row];
    unsigned hs = h2[(size_t)row * 64 + l];            // self-loop message
    float accx = dc * dc * bf2f_lo(hs);
    float accy = dc * dc * bf2f_hi(hs);
    int s0 = rowptr[row], s1 = rowptr[row + 1];
    for (int base = s0; base < s1; base += 64) {
        int idx = base + l;
        int sv = (idx < s1) ? srcs[idx] : 0;           // coalesced 64-wide
        float dv = (idx < s1) ? dis[sv] : 0.0f;
        int m = s1 - base; if (m > 64) m = 64;
        for (int j = 0; j < m; j++) {
            int r = __shfl(sv, j, 64);
            float norm = dc * __shfl(dv, j, 64);
            unsigned u = h2[(size_t)r * 64 + l];       // the only dependent gather
            accx += norm * bf2f_lo(u);
            accy += norm * bf2f_hi(u);
        }
    }
    // relu
    float v0 = accx > 0.0f ? accx : 0.0f;
    float v1 = accy > 0.0f ? accy : 0.0f;
    // layernorm over 128 cols via wave shuffle reduce
    float s1r = v0 + v1;
    float s2r = v0 * v0 + v1 * v1;
    #pragma unroll
    for (int m = 32; m >= 1; m >>= 1) {
        s1r += __shfl_xor(s1r, m, 64);
        s2r += __shfl_xor(s2r, m, 64);
    }
    float mean = s1r * (1.0f / 128.0f);
    float var  = s2r * (1.0f / 128.0f) - mean * mean;  // population var (jnp.var)
    float rstd = rsqrtf(var + 1e-5f);
    float2 g  = ((const float2*)gamma)[l];
    float2 bb = ((const float2*)beta)[l];
    float2 xx = ((const float2*)x)[(size_t)row * 64 + l];
    float2 o;
    o.x = (v0 - mean) * rstd * g.x + bb.x + xx.x;
    o.y = (v1 - mean) * rstd * g.y + bb.y + xx.y;
    ((float2*)out)[(size_t)row * 64 + l] = o;
}

extern "C" void kernel_launch(void* const* d_in, const int* in_sizes, int n_in,
                              void* d_out, int out_size, void* d_ws, size_t ws_size,
                              hipStream_t stream) {
    const float* x     = (const float*)d_in[0];
    const int*   ei    = (const int*)d_in[1];   // [2, E]
    const float* W     = (const float*)d_in[2];
    const float* bias  = (const float*)d_in[3];
    const float* gamma = (const float*)d_in[4];
    const float* beta  = (const float*)d_in[5];
    int N = in_sizes[0] / D;
    int E = in_sizes[1] / 2;
    int nb = (N + 255) / 256;                    // scan blocks (<=256 for N<=65536)

    char* ws = (char*)d_ws;
    size_t off = 0;
    unsigned short* xb   = (unsigned short*)(ws + off); off += (size_t)N * D * 2;   // 12.8 MB
    unsigned short* hb   = (unsigned short*)(ws + off); off += (size_t)N * D * 2;   // 12.8 MB
    unsigned short* wbf  = (unsigned short*)(ws + off); off += (size_t)D * D * 2;   // 32 KB
    unsigned* deg        = (unsigned*)(ws + off);       off += (size_t)N * 4;
    unsigned* cnt        = (unsigned*)(ws + off);       off += (size_t)N * 4;
    float*    dis        = (float*)(ws + off);          off += (size_t)N * 4;
    int*      rowptr     = (int*)(ws + off);            off += (size_t)(N + 1) * 4;
    unsigned* partial    = (unsigned*)(ws + off);       off += 256 * 4;
    int*      srcs       = (int*)(ws + off);            off += (size_t)E * 4;       // 3.2 MB
    float*    out        = (float*)d_out;

    hipMemsetAsync(deg, 0, (size_t)N * 4, stream);
    hipMemsetAsync(cnt, 0, (size_t)N * 4, stream);

    k_cast4<<<(N * D / 4 + 255) / 256, 256, 0, stream>>>((const float4*)x, (ushort4*)xb, N * D / 4);
    k_cast4<<<(D * D / 4 + 255) / 256, 256, 0, stream>>>((const float4*)W, (ushort4*)wbf, D * D / 4);
    k_hist<<<(E + 255) / 256, 256, 0, stream>>>(ei, E, deg, cnt);
    k_dis<<<(N + 255) / 256, 256, 0, stream>>>(deg, dis, N);
    k_partial<<<nb, 256, 0, stream>>>(cnt, N, partial);
    k_scanp<<<1, 256, 0, stream>>>(partial, nb);
    k_rowptr<<<nb, 256, 0, stream>>>(cnt, partial, N, E, rowptr);
    k_fill<<<(E + 255) / 256, 256, 0, stream>>>(ei, E, rowptr, cnt, srcs);
    k_gemm_mfma<<<(N / 16 + 3) / 4, 256, 0, stream>>>(xb, wbf, bias, hb, N);
    k_agg<<<(N + 3) / 4, 256, 0, stream>>>(x, hb, dis, rowptr, srcs, gamma, beta, out, N);
}

// Round 4
// 273.396 us; speedup vs baseline: 3.0505x; 1.0602x over previous
//
#include <hip/hip_runtime.h>

// ResGCNBlock: out = LN(relu(scatter_add(norm * (xW^T+b)[row] -> col))) + x
// N=50000, D=128, E=800000, fp32.
// Round 4: 8x-privatized histograms (atomic line-contention fix),
//          fused x->bf16 cast inside MFMA GEMM, k_dis merged into k_reduce.

#define D 128
#define NC 8   // privatized histogram copies

typedef short bf16x8 __attribute__((ext_vector_type(8)));
typedef float f32x4 __attribute__((ext_vector_type(4)));

__device__ __forceinline__ unsigned short f2bf(float f) {
    unsigned u = __float_as_uint(f);
    return (unsigned short)((u + 0x7fffu + ((u >> 16) & 1u)) >> 16);
}
__device__ __forceinline__ float bf2f_lo(unsigned v) { return __uint_as_float(v << 16); }
__device__ __forceinline__ float bf2f_hi(unsigned v) { return __uint_as_float(v & 0xffff0000u); }

// ---------- fp32 -> bf16 cast (W only), 4 elements/thread ----------
__global__ void k_cast4(const float4* __restrict__ src, ushort4* __restrict__ dst, int n4) {
    int i = blockIdx.x * 256 + threadIdx.x;
    if (i < n4) {
        float4 v = src[i];
        ushort4 o;
        o.x = f2bf(v.x); o.y = f2bf(v.y); o.z = f2bf(v.z); o.w = f2bf(v.w);
        dst[i] = o;
    }
}

// ---------- privatized histograms: copy = blockIdx & (NC-1) ----------
__global__ void k_hist(const int* __restrict__ ei, int E, int n,
                       unsigned* __restrict__ degc, unsigned* __restrict__ cntc) {
    int e = blockIdx.x * 256 + threadIdx.x;
    int c = blockIdx.x & (NC - 1);
    if (e < E) {
        atomicAdd(&degc[(size_t)c * n + ei[e]], 1u);        // source
        atomicAdd(&cntc[(size_t)c * n + ei[E + e]], 1u);    // dest
    }
}

// ---------- reduce copies: dis = rsqrt(deg+1), cnt total, per-copy prefixes ----------
__global__ void k_reduce(const unsigned* __restrict__ degc, const unsigned* __restrict__ cntc,
                         float* __restrict__ dis, unsigned* __restrict__ cnt,
                         unsigned* __restrict__ prefc, int n) {
    int i = blockIdx.x * 256 + threadIdx.x;
    if (i >= n) return;
    unsigned d = 0;
    #pragma unroll
    for (int c = 0; c < NC; c++) d += degc[(size_t)c * n + i];
    dis[i] = rsqrtf((float)d + 1.0f);                       // +1 = self loop
    unsigned run = 0;
    #pragma unroll
    for (int c = 0; c < NC; c++) {
        prefc[(size_t)c * n + i] = run;                     // exclusive over copies
        run += cntc[(size_t)c * n + i];
    }
    cnt[i] = run;
}

// ---------- scan pass 1: per-block partial sums of cnt ----------
__global__ void k_partial(const unsigned* __restrict__ cnt, int n,
                          unsigned* __restrict__ partial) {
    __shared__ unsigned s[256];
    int t = threadIdx.x;
    int i = blockIdx.x * 256 + t;
    s[t] = (i < n) ? cnt[i] : 0u;
    __syncthreads();
    #pragma unroll
    for (int d = 128; d > 0; d >>= 1) {
        if (t < d) s[t] += s[t + d];
        __syncthreads();
    }
    if (t == 0) partial[blockIdx.x] = s[0];
}

// ---------- scan pass 2: exclusive scan of partials (nb <= 256) ----------
__global__ void k_scanp(unsigned* __restrict__ partial, int nb) {
    __shared__ unsigned s[256];
    int t = threadIdx.x;
    unsigned v = (t < nb) ? partial[t] : 0u;
    s[t] = v;
    __syncthreads();
    #pragma unroll
    for (int d = 1; d < 256; d <<= 1) {
        unsigned u = (t >= d) ? s[t - d] : 0u;
        __syncthreads();
        s[t] += u;
        __syncthreads();
    }
    if (t < nb) partial[t] = s[t] - v;      // exclusive
}

// ---------- scan pass 3: block-local exclusive scan + offset -> rowptr ----------
__global__ void k_rowptr(const unsigned* __restrict__ cnt,
                         const unsigned* __restrict__ partial,
                         int n, int E, int* __restrict__ rowptr) {
    __shared__ unsigned s[256];
    int t = threadIdx.x;
    int i = blockIdx.x * 256 + t;
    unsigned v = (i < n) ? cnt[i] : 0u;
    s[t] = v;
    __syncthreads();
    #pragma unroll
    for (int d = 1; d < 256; d <<= 1) {
        unsigned u = (t >= d) ? s[t - d] : 0u;
        __syncthreads();
        s[t] += u;
        __syncthreads();
    }
    if (i < n) rowptr[i] = (int)(partial[blockIdx.x] + s[t] - v);
    if (blockIdx.x == 0 && t == 0) rowptr[n] = E;
}

// ---------- bucket fill: per-copy cursor, globally unique slots ----------
__global__ void k_fill(const int* __restrict__ ei, int E, int n,
                       const int* __restrict__ rowptr,
                       const unsigned* __restrict__ prefc, unsigned* __restrict__ cntc,
                       int* __restrict__ srcs) {
    int e = blockIdx.x * 256 + threadIdx.x;
    int c = blockIdx.x & (NC - 1);          // same mapping as k_hist
    if (e < E) {
        int r = ei[e];
        int v = ei[E + e];
        unsigned slot = atomicSub(&cntc[(size_t)c * n + v], 1u) - 1u;
        srcs[rowptr[v] + (int)prefc[(size_t)c * n + v] + (int)slot] = r;
    }
}

// ---------- h = x @ W^T + b via MFMA (x cast fused), output bf16 ----------
// 4 waves/block, each wave computes a 16x128 slab of h.
__global__ void k_gemm_mfma(const float* __restrict__ x,
                            const unsigned short* __restrict__ wb,
                            const float* __restrict__ bias,
                            unsigned short* __restrict__ hb, int nrows) {
    int wid = threadIdx.x >> 6, lane = threadIdx.x & 63;
    int m0 = (blockIdx.x * 4 + wid) * 16;
    if (m0 >= nrows) return;
    int lo16 = lane & 15, quad = lane >> 4;
    const float* arow = x + (size_t)(m0 + lo16) * D + quad * 8;
    bf16x8 a[4];
    #pragma unroll
    for (int kt = 0; kt < 4; kt++) {
        float4 p = *(const float4*)(arow + kt * 32);
        float4 q = *(const float4*)(arow + kt * 32 + 4);
        bf16x8 av;
        av[0] = (short)f2bf(p.x); av[1] = (short)f2bf(p.y);
        av[2] = (short)f2bf(p.z); av[3] = (short)f2bf(p.w);
        av[4] = (short)f2bf(q.x); av[5] = (short)f2bf(q.y);
        av[6] = (short)f2bf(q.z); av[7] = (short)f2bf(q.w);
        a[kt] = av;                                   // A[m=lo16][k=kt*32+quad*8 ..+7]
    }
    #pragma unroll
    for (int nt = 0; nt < 8; nt++) {
        int n0 = nt * 16;
        const unsigned short* brow = wb + (size_t)(n0 + lo16) * D + quad * 8;
        float bj = bias[n0 + lo16];                   // C col = lane&15
        f32x4 acc = {bj, bj, bj, bj};
        #pragma unroll
        for (int kt = 0; kt < 4; kt++) {
            bf16x8 b = *(const bf16x8*)(brow + kt * 32);
            acc = __builtin_amdgcn_mfma_f32_16x16x32_bf16(a[kt], b, acc, 0, 0, 0);
        }
        #pragma unroll
        for (int r = 0; r < 4; r++) {                 // C row = quad*4 + r
            int gr = m0 + quad * 4 + r;
            hb[(size_t)gr * D + n0 + lo16] = f2bf(acc[r]);
        }
    }
}

// ---------- fused gather-aggregate + self-loop + relu + LN + residual ----------
// one wave per dest row; lane l owns cols (2l, 2l+1); h is bf16 (4 B/lane/edge).
__global__ void k_agg(const float* __restrict__ x, const unsigned short* __restrict__ hb,
                      const float* __restrict__ dis,
                      const int* __restrict__ rowptr, const int* __restrict__ srcs,
                      const float* __restrict__ gamma, const float* __restrict__ beta,
                      float* __restrict__ out, int n) {
    int w = threadIdx.x >> 6, l = threadIdx.x & 63;
    int row = blockIdx.x * 4 + w;
    if (row >= n) return;
    const unsigned* h2 = (const unsigned*)hb;          // 2 bf16 cols per load
    float dc = dis[row];
    unsigned hs = h2[(size_t)row * 64 + l];            // self-loop message
    float accx = dc * dc * bf2f_lo(hs);
    float accy = dc * dc * bf2f_hi(hs);
    int s0 = rowptr[row], s1 = rowptr[row + 1];
    for (int base = s0; base < s1; base += 64) {
        int idx = base + l;
        int sv = (idx < s1) ? srcs[idx] : 0;           // coalesced 64-wide
        float dv = (idx < s1) ? dis[sv] : 0.0f;
        int m = s1 - base; if (m > 64) m = 64;
        for (int j = 0; j < m; j++) {
            int r = __shfl(sv, j, 64);
            float norm = dc * __shfl(dv, j, 64);
            unsigned u = h2[(size_t)r * 64 + l];       // the only dependent gather
            accx += norm * bf2f_lo(u);
            accy += norm * bf2f_hi(u);
        }
    }
    float v0 = accx > 0.0f ? accx : 0.0f;              // relu
    float v1 = accy > 0.0f ? accy : 0.0f;
    float s1r = v0 + v1;                               // LN via wave shuffle reduce
    float s2r = v0 * v0 + v1 * v1;
    #pragma unroll
    for (int m = 32; m >= 1; m >>= 1) {
        s1r += __shfl_xor(s1r, m, 64);
        s2r += __shfl_xor(s2r, m, 64);
    }
    float mean = s1r * (1.0f / 128.0f);
    float var  = s2r * (1.0f / 128.0f) - mean * mean;  // population var (jnp.var)
    float rstd = rsqrtf(var + 1e-5f);
    float2 g  = ((const float2*)gamma)[l];
    float2 bb = ((const float2*)beta)[l];
    float2 xx = ((const float2*)x)[(size_t)row * 64 + l];
    float2 o;
    o.x = (v0 - mean) * rstd * g.x + bb.x + xx.x;
    o.y = (v1 - mean) * rstd * g.y + bb.y + xx.y;
    ((float2*)out)[(size_t)row * 64 + l] = o;
}

extern "C" void kernel_launch(void* const* d_in, const int* in_sizes, int n_in,
                              void* d_out, int out_size, void* d_ws, size_t ws_size,
                              hipStream_t stream) {
    const float* x     = (const float*)d_in[0];
    const int*   ei    = (const int*)d_in[1];   // [2, E]
    const float* W     = (const float*)d_in[2];
    const float* bias  = (const float*)d_in[3];
    const float* gamma = (const float*)d_in[4];
    const float* beta  = (const float*)d_in[5];
    int N = in_sizes[0] / D;
    int E = in_sizes[1] / 2;
    int nb  = (N + 255) / 256;                   // scan blocks (<=256 for N<=65536)
    int nbE = (E + 255) / 256;

    char* ws = (char*)d_ws;
    size_t off = 0;
    unsigned short* hb   = (unsigned short*)(ws + off); off += (size_t)N * D * 2;       // 12.8 MB
    unsigned short* wbf  = (unsigned short*)(ws + off); off += (size_t)D * D * 2;       // 32 KB
    unsigned* degc       = (unsigned*)(ws + off);       off += (size_t)NC * N * 4;      // 1.6 MB
    unsigned* cntc       = (unsigned*)(ws + off);       off += (size_t)NC * N * 4;      // 1.6 MB
    unsigned* prefc      = (unsigned*)(ws + off);       off += (size_t)NC * N * 4;      // 1.6 MB
    float*    dis        = (float*)(ws + off);          off += (size_t)N * 4;
    unsigned* cnt        = (unsigned*)(ws + off);       off += (size_t)N * 4;
    int*      rowptr     = (int*)(ws + off);            off += (size_t)(N + 1) * 4;
    unsigned* partial    = (unsigned*)(ws + off);       off += 256 * 4;
    int*      srcs       = (int*)(ws + off);            off += (size_t)E * 4;           // 3.2 MB
    float*    out        = (float*)d_out;

    hipMemsetAsync(degc, 0, (size_t)NC * N * 4, stream);
    hipMemsetAsync(cntc, 0, (size_t)NC * N * 4, stream);

    k_cast4<<<(D * D / 4 + 255) / 256, 256, 0, stream>>>((const float4*)W, (ushort4*)wbf, D * D / 4);
    k_hist<<<nbE, 256, 0, stream>>>(ei, E, N, degc, cntc);
    k_reduce<<<nb, 256, 0, stream>>>(degc, cntc, dis, cnt, prefc, N);
    k_partial<<<nb, 256, 0, stream>>>(cnt, N, partial);
    k_scanp<<<1, 256, 0, stream>>>(partial, nb);
    k_rowptr<<<nb, 256, 0, stream>>>(cnt, partial, N, E, rowptr);
    k_fill<<<nbE, 256, 0, stream>>>(ei, E, N, rowptr, prefc, cntc, srcs);
    k_gemm_mfma<<<(N / 16 + 3) / 4, 256, 0, stream>>>(x, wbf, bias, hb, N);
    k_agg<<<(N + 3) / 4, 256, 0, stream>>>(x, hb, dis, rowptr, srcs, gamma, beta, out, N);
}

// Round 6
// 230.773 us; speedup vs baseline: 3.6139x; 1.1847x over previous
//
#include <hip/hip_runtime.h>

// ResGCNBlock: out = LN(relu(scatter_add(norm * (xW^T+b)[row] -> col))) + x
// N=50000, D=128, E=800000, fp32.
// Round 6: device-scope rank-carrying histogram (atomic-free k_fill),
//          GEMM merged under the histogram, single-copy counters (no k_reduce).
//          k_agg = proven round-4 structure.

#define D 128

typedef short bf16x8 __attribute__((ext_vector_type(8)));
typedef float f32x4 __attribute__((ext_vector_type(4)));

__device__ __forceinline__ unsigned short f2bf(float f) {
    unsigned u = __float_as_uint(f);
    return (unsigned short)((u + 0x7fffu + ((u >> 16) & 1u)) >> 16);
}
__device__ __forceinline__ float bf2f_lo(unsigned v) { return __uint_as_float(v << 16); }
__device__ __forceinline__ float bf2f_hi(unsigned v) { return __uint_as_float(v & 0xffff0000u); }

// ---------- fp32 -> bf16 cast (W only), 4 elements/thread ----------
__global__ void k_cast4(const float4* __restrict__ src, ushort4* __restrict__ dst, int n4) {
    int i = blockIdx.x * 256 + threadIdx.x;
    if (i < n4) {
        float4 v = src[i];
        ushort4 o;
        o.x = f2bf(v.x); o.y = f2bf(v.y); o.z = f2bf(v.z); o.w = f2bf(v.w);
        dst[i] = o;
    }
}

// ---------- merged: MFMA GEMM blocks + histogram blocks (independent work) ----------
// GEMM: h = x @ W^T + b (bf16 out). Hist: device-scope atomics; the cnt atomic's
// return value is the edge's unique rank within its dest bucket -> aux.
__global__ void k_gemm_hist(const float* __restrict__ x, const unsigned short* __restrict__ wb,
                            const float* __restrict__ bias, unsigned short* __restrict__ hb,
                            int nrows,
                            const int* __restrict__ ei, int E,
                            unsigned* __restrict__ deg, unsigned* __restrict__ cnt,
                            unsigned* __restrict__ aux, int gemm_blocks) {
    if ((int)blockIdx.x < gemm_blocks) {
        // ---- GEMM role: 4 waves/block, each wave a 16x128 slab of h ----
        int wid = threadIdx.x >> 6, lane = threadIdx.x & 63;
        int m0 = ((int)blockIdx.x * 4 + wid) * 16;
        if (m0 >= nrows) return;
        int lo16 = lane & 15, quad = lane >> 4;
        const float* arow = x + (size_t)(m0 + lo16) * D + quad * 8;
        bf16x8 a[4];
        #pragma unroll
        for (int kt = 0; kt < 4; kt++) {
            float4 p = *(const float4*)(arow + kt * 32);
            float4 q = *(const float4*)(arow + kt * 32 + 4);
            bf16x8 av;
            av[0] = (short)f2bf(p.x); av[1] = (short)f2bf(p.y);
            av[2] = (short)f2bf(p.z); av[3] = (short)f2bf(p.w);
            av[4] = (short)f2bf(q.x); av[5] = (short)f2bf(q.y);
            av[6] = (short)f2bf(q.z); av[7] = (short)f2bf(q.w);
            a[kt] = av;
        }
        #pragma unroll
        for (int nt = 0; nt < 8; nt++) {
            int n0 = nt * 16;
            const unsigned short* brow = wb + (size_t)(n0 + lo16) * D + quad * 8;
            float bj = bias[n0 + lo16];
            f32x4 acc = {bj, bj, bj, bj};
            #pragma unroll
            for (int kt = 0; kt < 4; kt++) {
                bf16x8 b = *(const bf16x8*)(brow + kt * 32);
                acc = __builtin_amdgcn_mfma_f32_16x16x32_bf16(a[kt], b, acc, 0, 0, 0);
            }
            #pragma unroll
            for (int r = 0; r < 4; r++) {
                int gr = m0 + quad * 4 + r;
                hb[(size_t)gr * D + n0 + lo16] = f2bf(acc[r]);
            }
        }
    } else {
        // ---- Histogram role: device-scope atomics (proven path) ----
        int e = ((int)blockIdx.x - gemm_blocks) * 256 + threadIdx.x;
        if (e < E) {
            int r = ei[e];        // source -> deg
            int v = ei[E + e];    // dest   -> cnt (+rank)
            atomicAdd(&deg[r], 1u);
            unsigned rank = atomicAdd(&cnt[v], 1u);   // unique slot in dest bucket
            aux[e] = rank;
        }
    }
}

// ---------- dis = rsqrt(deg+1); per-block partial sums of cnt ----------
__global__ void k_partial(const unsigned* __restrict__ deg, const unsigned* __restrict__ cnt,
                          float* __restrict__ dis, unsigned* __restrict__ partial, int n) {
    __shared__ unsigned s[256];
    int t = threadIdx.x;
    int i = blockIdx.x * 256 + t;
    unsigned c = 0;
    if (i < n) {
        dis[i] = rsqrtf((float)deg[i] + 1.0f);   // +1 = self loop
        c = cnt[i];
    }
    s[t] = c;
    __syncthreads();
    #pragma unroll
    for (int d = 128; d > 0; d >>= 1) {
        if (t < d) s[t] += s[t + d];
        __syncthreads();
    }
    if (t == 0) partial[blockIdx.x] = s[0];
}

// ---------- exclusive scan of partials (nb <= 256) ----------
__global__ void k_scanp(unsigned* __restrict__ partial, int nb) {
    __shared__ unsigned s[256];
    int t = threadIdx.x;
    unsigned v = (t < nb) ? partial[t] : 0u;
    s[t] = v;
    __syncthreads();
    #pragma unroll
    for (int d = 1; d < 256; d <<= 1) {
        unsigned u = (t >= d) ? s[t - d] : 0u;
        __syncthreads();
        s[t] += u;
        __syncthreads();
    }
    if (t < nb) partial[t] = s[t] - v;      // exclusive
}

// ---------- block-local exclusive scan + offset -> rowptr ----------
__global__ void k_rowptr(const unsigned* __restrict__ cnt,
                         const unsigned* __restrict__ partial,
                         int n, int E, int* __restrict__ rowptr) {
    __shared__ unsigned s[256];
    int t = threadIdx.x;
    int i = blockIdx.x * 256 + t;
    unsigned v = (i < n) ? cnt[i] : 0u;
    s[t] = v;
    __syncthreads();
    #pragma unroll
    for (int d = 1; d < 256; d <<= 1) {
        unsigned u = (t >= d) ? s[t - d] : 0u;
        __syncthreads();
        s[t] += u;
        __syncthreads();
    }
    if (i < n) rowptr[i] = (int)(partial[blockIdx.x] + s[t] - v);
    if (blockIdx.x == 0 && t == 0) rowptr[n] = E;
}

// ---------- atomic-free bucket fill using precomputed rank ----------
__global__ void k_fill(const int* __restrict__ ei, int E,
                       const int* __restrict__ rowptr, const unsigned* __restrict__ aux,
                       int* __restrict__ srcs) {
    int e = blockIdx.x * 256 + threadIdx.x;
    if (e < E) {
        int r = ei[e];
        int v = ei[E + e];
        srcs[rowptr[v] + (int)aux[e]] = r;
    }
}

// ---------- fused gather-aggregate + self-loop + relu + LN + residual ----------
// one wave per dest row; lane l owns cols (2l, 2l+1); h is bf16 (4 B/lane/edge).
__global__ void k_agg(const float* __restrict__ x, const unsigned short* __restrict__ hb,
                      const float* __restrict__ dis,
                      const int* __restrict__ rowptr, const int* __restrict__ srcs,
                      const float* __restrict__ gamma, const float* __restrict__ beta,
                      float* __restrict__ out, int n) {
    int w = threadIdx.x >> 6, l = threadIdx.x & 63;
    int row = blockIdx.x * 4 + w;
    if (row >= n) return;
    const unsigned* h2 = (const unsigned*)hb;          // 2 bf16 cols per load
    float dc = dis[row];
    unsigned hs = h2[(size_t)row * 64 + l];            // self-loop message
    float accx = dc * dc * bf2f_lo(hs);
    float accy = dc * dc * bf2f_hi(hs);
    int s0 = rowptr[row], s1 = rowptr[row + 1];
    for (int base = s0; base < s1; base += 64) {
        int idx = base + l;
        int sv = (idx < s1) ? srcs[idx] : 0;           // coalesced 64-wide
        float dv = (idx < s1) ? dis[sv] : 0.0f;
        int m = s1 - base; if (m > 64) m = 64;
        #pragma unroll 2
        for (int j = 0; j < m; j++) {
            int r = __shfl(sv, j, 64);
            float norm = dc * __shfl(dv, j, 64);
            unsigned u = h2[(size_t)r * 64 + l];       // the only dependent gather
            accx += norm * bf2f_lo(u);
            accy += norm * bf2f_hi(u);
        }
    }
    float v0 = accx > 0.0f ? accx : 0.0f;              // relu
    float v1 = accy > 0.0f ? accy : 0.0f;
    float s1r = v0 + v1;                               // LN via wave shuffle reduce
    float s2r = v0 * v0 + v1 * v1;
    #pragma unroll
    for (int m = 32; m >= 1; m >>= 1) {
        s1r += __shfl_xor(s1r, m, 64);
        s2r += __shfl_xor(s2r, m, 64);
    }
    float mean = s1r * (1.0f / 128.0f);
    float var  = s2r * (1.0f / 128.0f) - mean * mean;  // population var (jnp.var)
    float rstd = rsqrtf(var + 1e-5f);
    float2 g  = ((const float2*)gamma)[l];
    float2 bb = ((const float2*)beta)[l];
    float2 xx = ((const float2*)x)[(size_t)row * 64 + l];
    float2 o;
    o.x = (v0 - mean) * rstd * g.x + bb.x + xx.x;
    o.y = (v1 - mean) * rstd * g.y + bb.y + xx.y;
    ((float2*)out)[(size_t)row * 64 + l] = o;
}

extern "C" void kernel_launch(void* const* d_in, const int* in_sizes, int n_in,
                              void* d_out, int out_size, void* d_ws, size_t ws_size,
                              hipStream_t stream) {
    const float* x     = (const float*)d_in[0];
    const int*   ei    = (const int*)d_in[1];   // [2, E]
    const float* W     = (const float*)d_in[2];
    const float* bias  = (const float*)d_in[3];
    const float* gamma = (const float*)d_in[4];
    const float* beta  = (const float*)d_in[5];
    int N = in_sizes[0] / D;
    int E = in_sizes[1] / 2;
    int nb  = (N + 255) / 256;                   // 196 scan blocks (<=256)
    int nbE = (E + 255) / 256;                   // 3125
    int gemm_blocks = (N / 16 + 3) / 4;          // 782

    char* ws = (char*)d_ws;
    size_t off = 0;
    unsigned short* hb  = (unsigned short*)(ws + off); off += (size_t)N * D * 2;   // 12.8 MB
    unsigned short* wbf = (unsigned short*)(ws + off); off += (size_t)D * D * 2;   // 32 KB
    unsigned* deg       = (unsigned*)(ws + off);       off += (size_t)N * 4;       // contiguous
    unsigned* cnt       = (unsigned*)(ws + off);       off += (size_t)N * 4;       //  with deg
    float*    dis       = (float*)(ws + off);          off += (size_t)N * 4;
    int*      rowptr    = (int*)(ws + off);            off += (size_t)(N + 1) * 4;
    unsigned* partial   = (unsigned*)(ws + off);       off += 256 * 4;
    unsigned* aux       = (unsigned*)(ws + off);       off += (size_t)E * 4;       // 3.2 MB
    int*      srcs      = (int*)(ws + off);            off += (size_t)E * 4;       // 3.2 MB
    float*    out       = (float*)d_out;

    hipMemsetAsync(deg, 0, (size_t)2 * N * 4, stream);   // deg + cnt

    k_cast4<<<(D * D / 4 + 255) / 256, 256, 0, stream>>>((const float4*)W, (ushort4*)wbf, D * D / 4);
    k_gemm_hist<<<gemm_blocks + nbE, 256, 0, stream>>>(x, wbf, bias, hb, N,
                                                       ei, E, deg, cnt, aux, gemm_blocks);
    k_partial<<<nb, 256, 0, stream>>>(deg, cnt, dis, partial, N);
    k_scanp<<<1, 256, 0, stream>>>(partial, nb);
    k_rowptr<<<nb, 256, 0, stream>>>(cnt, partial, N, E, rowptr);
    k_fill<<<nbE, 256, 0, stream>>>(ei, E, rowptr, aux, srcs);
    k_agg<<<(N + 3) / 4, 256, 0, stream>>>(x, hb, dis, rowptr, srcs, gamma, beta, out, N);
}